// Round 1
// baseline (726.214 us; speedup 1.0000x reference)
//
#include <hip/hip_runtime.h>
#include <math.h>

// Problem constants (fixed by the reference)
#define TOK    2048      // B*S
#define DMODEL 1024
#define NHEAD  16
#define HDIM   64
#define NEXP   8
#define DFFN   4096

typedef unsigned short u16;
typedef __attribute__((ext_vector_type(8))) short short8;   // 8 bf16 (4 VGPRs)
typedef __attribute__((ext_vector_type(4))) float floatx4;  // MFMA C/D

__device__ __forceinline__ float sigmoidf_(float x) { return 1.f / (1.f + expf(-x)); }

__device__ __forceinline__ u16 f2bf(float f) {               // RNE fp32->bf16
  union { float f; unsigned u; } v; v.f = f;
  unsigned r = v.u + 0x7FFFu + ((v.u >> 16) & 1u);
  return (u16)(r >> 16);
}
__device__ __forceinline__ float bf2f(u16 h) {
  union { unsigned u; float f; } v; v.u = ((unsigned)h) << 16; return v.f;
}

// async global->LDS, 16B per lane; LDS dest = wave-uniform base + lane*16
__device__ __forceinline__ void gload16(const void* g, void* l) {
  __builtin_amdgcn_global_load_lds((const __attribute__((address_space(1))) void*)g,
                                   (__attribute__((address_space(3))) void*)l, 16, 0, 0);
}

// block = 256 threads (4 waves). Broadcast result to all threads.
__device__ __forceinline__ float blockReduceSum256(float val) {
  __shared__ float ws_[4];
  #pragma unroll
  for (int off = 32; off; off >>= 1) val += __shfl_down(val, off);
  int lane = threadIdx.x & 63, w = threadIdx.x >> 6;
  if (lane == 0) ws_[w] = val;
  __syncthreads();
  float r = ws_[0] + ws_[1] + ws_[2] + ws_[3];
  __syncthreads();
  return r;
}

// ---------------------------------------------------------------------------
// fp32 -> (hi, lo) bf16 split, elementwise. grid = n/1024, 4 floats/thread.
// ---------------------------------------------------------------------------
__global__ __launch_bounds__(256) void split_kernel(
    const float* __restrict__ X, u16* __restrict__ Hi, u16* __restrict__ Lo) {
  const int i = blockIdx.x * 256 + threadIdx.x;
  const float4 v = ((const float4*)X)[i];
  const float f[4] = {v.x, v.y, v.z, v.w};
  union { u16 s[4]; uint2 u; } h, l;
  #pragma unroll
  for (int j = 0; j < 4; ++j) {
    h.s[j] = f2bf(f[j]);
    l.s[j] = f2bf(f[j] - bf2f(h.s[j]));
  }
  ((uint2*)Hi)[i] = h.u;
  ((uint2*)Lo)[i] = l.u;
}

// ---------------------------------------------------------------------------
// Weight convert+transpose: W[K][N] fp32 -> Wt_hi[N][K] bf16 (+ optional lo).
// blockIdx.z = batch (expert); strides K*N. 32x32 LDS tile.
// ---------------------------------------------------------------------------
template<bool LO>
__global__ __launch_bounds__(256) void wt_conv_kernel(
    const float* __restrict__ W, u16* __restrict__ Whi, u16* __restrict__ Wlo,
    int K, int N) {
  const size_t z = blockIdx.z;
  W   += z * (size_t)K * N;
  Whi += z * (size_t)K * N;
  if (LO) Wlo += z * (size_t)K * N;
  __shared__ float tile[32][33];
  const int n0 = blockIdx.x * 32, k0 = blockIdx.y * 32;
  const int r = threadIdx.x >> 3, c4 = (threadIdx.x & 7) * 4;
  const float4 v = *(const float4*)&W[(size_t)(k0 + r) * N + n0 + c4];
  tile[r][c4+0] = v.x; tile[r][c4+1] = v.y; tile[r][c4+2] = v.z; tile[r][c4+3] = v.w;
  __syncthreads();
  union { u16 s[4]; uint2 u; } h, l;
  #pragma unroll
  for (int j = 0; j < 4; ++j) {
    const float f = tile[c4 + j][r];
    h.s[j] = f2bf(f);
    if (LO) l.s[j] = f2bf(f - bf2f(h.s[j]));
  }
  *(uint2*)&Whi[(size_t)(n0 + r) * K + k0 + c4] = h.u;
  if (LO) *(uint2*)&Wlo[(size_t)(n0 + r) * K + k0 + c4] = l.u;
}

// Fused QKV weight conversion: z selects {qw, kw, vw} (32 z-slices each).
__global__ __launch_bounds__(256) void wt3_conv_kernel(
    const float* __restrict__ Q, const float* __restrict__ Kw,
    const float* __restrict__ V, u16* __restrict__ Whi, u16* __restrict__ Wlo) {
  const int zz = blockIdx.z >> 5;              // 0,1,2
  const float* W = (zz == 0) ? Q : (zz == 1) ? Kw : V;
  u16* Whi_ = Whi + (size_t)zz * DMODEL * DMODEL;
  u16* Wlo_ = Wlo + (size_t)zz * DMODEL * DMODEL;
  __shared__ float tile[32][33];
  const int n0 = blockIdx.x * 32, k0 = (blockIdx.z & 31) * 32;
  const int r = threadIdx.x >> 3, c4 = (threadIdx.x & 7) * 4;
  const float4 v = *(const float4*)&W[(size_t)(k0 + r) * DMODEL + n0 + c4];
  tile[r][c4+0] = v.x; tile[r][c4+1] = v.y; tile[r][c4+2] = v.z; tile[r][c4+3] = v.w;
  __syncthreads();
  union { u16 s[4]; uint2 u; } h, l;
  #pragma unroll
  for (int j = 0; j < 4; ++j) {
    const float f = tile[c4 + j][r];
    h.s[j] = f2bf(f);
    l.s[j] = f2bf(f - bf2f(h.s[j]));
  }
  *(uint2*)&Whi_[(size_t)(n0 + r) * DMODEL + k0 + c4] = h.u;
  *(uint2*)&Wlo_[(size_t)(n0 + r) * DMODEL + k0 + c4] = l.u;
}

// ---------------------------------------------------------------------------
// Split-precision bf16 MFMA GEMM: C[M,N] = A[M,K] @ W[K,N].
// A as (Ahi,Alo) bf16 [M][K]; W transposed (Whi,Wlo) bf16 [N][K].
// acc += Ah*Wh + Al*Wh + Ah*Wl  (error ~2^-18, protects MoE routing).
// Tile 128(M) x TN(N), BK=64, 4 waves 2x2 (wave tile 64 x TN/2), 16x16x32 MFMA.
// LDS chunk-swizzle: chunk c of row m holds global k-chunk (c ^ (m&7)).
// EPI 0: Cf = acc (fp32).
// EPI 1: g = sigmoid(acc+bias[n])*mul[m,n] -> Chi/Clo split.
// EPI 2: QKV path. cols < 2048 (Q,K): Chi/Clo = split(acc) row-major.
//        cols >= 2048 (V): store transposed into Vt[bh][d][tok] hi/lo
//        (4 acc rows = 4 consecutive tokens -> packed 8B store).
// ---------------------------------------------------------------------------
template<int EPI, int TN>
__global__ __launch_bounds__(256, TN == 64 ? 3 : 2) void gemm_split_kernel(
    const u16* __restrict__ Ahi, const u16* __restrict__ Alo,
    const u16* __restrict__ Whi, const u16* __restrict__ Wlo,
    const float* __restrict__ bias, const float* __restrict__ mul,
    float* __restrict__ Cf, u16* __restrict__ Chi, u16* __restrict__ Clo,
    u16* __restrict__ Vth, u16* __restrict__ Vtl,
    int M, int N, int K) {
  constexpr int NF = TN / 32;                    // B n-frags per wave (2 or 4)
  __shared__ u16 Ah[128*64], Al[128*64], Bh[TN*64], Bl[TN*64];
  const int tid = threadIdx.x;
  const int lane = tid & 63, wave = tid >> 6;
  const int row0 = blockIdx.y * 128, col0 = blockIdx.x * TN;
  const int wm = (wave & 1) * 64, wn = (wave >> 1) * (TN / 2);
  const int mr = tid >> 3;                       // staging row 0..31 (+p*32)
  const int ksrc = (tid & 7) ^ ((tid >> 3) & 7); // swizzled source k-chunk
  const floatx4 zero = {0.f, 0.f, 0.f, 0.f};
  floatx4 acc[4][NF];
  #pragma unroll
  for (int i = 0; i < 4; ++i)
    #pragma unroll
    for (int j = 0; j < NF; ++j) acc[i][j] = zero;

  for (int k0 = 0; k0 < K; k0 += 64) {
    __syncthreads();
    #pragma unroll
    for (int p = 0; p < 4; ++p) {               // A: 128 rows
      const size_t ga = (size_t)(row0 + p * 32 + mr) * K + (k0 + ksrc * 8);
      const size_t off = (size_t)(p * 256 + wave * 64) * 16;
      gload16(Ahi + ga, (char*)Ah + off);
      gload16(Alo + ga, (char*)Al + off);
    }
    #pragma unroll
    for (int p = 0; p < NF; ++p) {              // B: TN rows
      const size_t gb = (size_t)(col0 + p * 32 + mr) * K + (k0 + ksrc * 8);
      const size_t off = (size_t)(p * 256 + wave * 64) * 16;
      gload16(Whi + gb, (char*)Bh + off);
      gload16(Wlo + gb, (char*)Bl + off);
    }
    __syncthreads();
    #pragma unroll
    for (int kk = 0; kk < 2; ++kk) {
      short8 ah[4], al[4], bh[NF], bl[NF];
      #pragma unroll
      for (int i = 0; i < 4; ++i) {
        const int ml = wm + i * 16 + (lane & 15);
        const int cm = (kk * 4 + (lane >> 4)) ^ (ml & 7);
        ah[i] = *(const short8*)&Ah[ml * 64 + cm * 8];
        al[i] = *(const short8*)&Al[ml * 64 + cm * 8];
      }
      #pragma unroll
      for (int j = 0; j < NF; ++j) {
        const int nl = wn + j * 16 + (lane & 15);
        const int cn = (kk * 4 + (lane >> 4)) ^ (nl & 7);
        bh[j] = *(const short8*)&Bh[nl * 64 + cn * 8];
        bl[j] = *(const short8*)&Bl[nl * 64 + cn * 8];
      }
      #pragma unroll
      for (int i = 0; i < 4; ++i)
        #pragma unroll
        for (int j = 0; j < NF; ++j) {
          acc[i][j] = __builtin_amdgcn_mfma_f32_16x16x32_bf16(ah[i], bh[j], acc[i][j], 0, 0, 0);
          acc[i][j] = __builtin_amdgcn_mfma_f32_16x16x32_bf16(al[i], bh[j], acc[i][j], 0, 0, 0);
          acc[i][j] = __builtin_amdgcn_mfma_f32_16x16x32_bf16(ah[i], bl[j], acc[i][j], 0, 0, 0);
        }
    }
  }
  const int cl = lane & 15, quad = lane >> 4;
  if (EPI == 2 && col0 >= 2048) {
    // V region: transposed store into Vt[bh][d][tok] (hi/lo), 8B packed.
    #pragma unroll
    for (int i = 0; i < 4; ++i)
      #pragma unroll
      for (int j = 0; j < NF; ++j) {
        const int dg = col0 + wn + j * 16 + cl - 2048;
        const int bh_ = dg >> 6, d = dg & 63;
        const int row = row0 + wm + i * 16 + quad * 4;   // +r, 4 consecutive toks
        const int b = row >> 10, t0 = row & 1023;
        union { u16 s[4]; uint2 u; } hh, ll;
        #pragma unroll
        for (int r = 0; r < 4; ++r) {
          const float v = acc[i][j][r];
          hh.s[r] = f2bf(v);
          ll.s[r] = f2bf(v - bf2f(hh.s[r]));
        }
        const size_t base = ((size_t)(b * 16 + bh_) * 64 + d) * 1024 + t0;
        *(uint2*)&Vth[base] = hh.u;
        *(uint2*)&Vtl[base] = ll.u;
      }
    return;
  }
  #pragma unroll
  for (int i = 0; i < 4; ++i)
    #pragma unroll
    for (int j = 0; j < NF; ++j) {
      const int col = col0 + wn + j * 16 + cl;
      #pragma unroll
      for (int r = 0; r < 4; ++r) {
        const int row = row0 + wm + i * 16 + quad * 4 + r;
        const float v = acc[i][j][r];
        if (EPI == 0) {
          Cf[(size_t)row * N + col] = v;
        } else if (EPI == 1) {
          const float s = sigmoidf_(v + bias[col]);
          const float g = s * mul[(size_t)row * N + col];
          const u16 hh = f2bf(g);
          Chi[(size_t)row * N + col] = hh;
          Clo[(size_t)row * N + col] = f2bf(g - bf2f(hh));
        } else {
          const u16 hh = f2bf(v);
          Chi[(size_t)row * N + col] = hh;
          Clo[(size_t)row * N + col] = f2bf(v - bf2f(hh));
        }
      }
    }
}

// ---------------------------------------------------------------------------
// Grouped MoE GEMM, plain bf16 MFMA. Tile 128(M) x TN(N), 4 waves 2x2.
// EPI 0 (ffn1): z = local expert (4); full K. Hout = bf16(acc + bias[e][n]).
// EPI 1 (ffn2): z = ez + 4*ks (8): 2-way split-K; P[ks][tok*N+col] = acc fp32.
// ---------------------------------------------------------------------------
template<int EPI, int TN>
__global__ __launch_bounds__(256, TN == 64 ? 4 : 3) void gemm_moe_kernel(
    const u16* __restrict__ A, const u16* __restrict__ Wt,
    const float* __restrict__ bias,
    const int* __restrict__ perm, const int* __restrict__ offs,
    const int* __restrict__ counts,
    u16* __restrict__ Hout, float* __restrict__ P0, float* __restrict__ P1,
    int N, int K, int e_base) {
  constexpr int NF = TN / 32;
  const int z = blockIdx.z;
  const int ez = (EPI == 0) ? z : (z & 3);
  const int ks = (EPI == 0) ? 0 : (z >> 2);
  const int e = e_base + ez;
  const int ne = counts[e];
  const int tm = blockIdx.y;
  if (tm * 128 >= ne) return;
  const int kbeg = (EPI == 0) ? 0 : ks * (K >> 1);
  const int kend = (EPI == 0) ? K : kbeg + (K >> 1);
  __shared__ u16 As_[128*64], Bs_[TN*64];
  __shared__ int toks[128];
  const int tid = threadIdx.x;
  if (tid < 128) {
    const int idx = tm * 128 + tid;
    toks[tid] = perm[offs[e] + (idx < ne ? idx : 0)];
  }
  __syncthreads();
  const int lane = tid & 63, wave = tid >> 6;
  const int wm = (wave & 1) * 64, wn = (wave >> 1) * (TN / 2);
  const int mr = tid >> 3;
  const int ksrc = (tid & 7) ^ ((tid >> 3) & 7);
  size_t abase[4];
  #pragma unroll
  for (int p = 0; p < 4; ++p) abase[p] = (size_t)toks[p * 32 + mr] * K;
  const u16* We = Wt + (size_t)ez * N * K;
  const int col0 = blockIdx.x * TN;
  const floatx4 zero = {0.f, 0.f, 0.f, 0.f};
  floatx4 acc[4][NF];
  #pragma unroll
  for (int i = 0; i < 4; ++i)
    #pragma unroll
    for (int j = 0; j < NF; ++j) acc[i][j] = zero;

  for (int k0 = kbeg; k0 < kend; k0 += 64) {
    __syncthreads();
    #pragma unroll
    for (int p = 0; p < 4; ++p) {
      const size_t off = (size_t)(p * 256 + wave * 64) * 16;
      gload16(A + abase[p] + (k0 + ksrc * 8), (char*)As_ + off);
    }
    #pragma unroll
    for (int p = 0; p < NF; ++p) {
      const size_t off = (size_t)(p * 256 + wave * 64) * 16;
      gload16(We + (size_t)(col0 + p * 32 + mr) * K + (k0 + ksrc * 8), (char*)Bs_ + off);
    }
    __syncthreads();
    #pragma unroll
    for (int kk = 0; kk < 2; ++kk) {
      short8 a[4], b[NF];
      #pragma unroll
      for (int i = 0; i < 4; ++i) {
        const int ml = wm + i * 16 + (lane & 15);
        const int cm = (kk * 4 + (lane >> 4)) ^ (ml & 7);
        a[i] = *(const short8*)&As_[ml * 64 + cm * 8];
      }
      #pragma unroll
      for (int j = 0; j < NF; ++j) {
        const int nl = wn + j * 16 + (lane & 15);
        const int cn = (kk * 4 + (lane >> 4)) ^ (nl & 7);
        b[j] = *(const short8*)&Bs_[nl * 64 + cn * 8];
      }
      #pragma unroll
      for (int i = 0; i < 4; ++i)
        #pragma unroll
        for (int j = 0; j < NF; ++j)
          acc[i][j] = __builtin_amdgcn_mfma_f32_16x16x32_bf16(a[i], b[j], acc[i][j], 0, 0, 0);
    }
  }
  const int cl = lane & 15, quad = lane >> 4;
  float* Pp = (EPI == 1) ? (ks ? P1 : P0) : nullptr;
  #pragma unroll
  for (int i = 0; i < 4; ++i)
    #pragma unroll
    for (int j = 0; j < NF; ++j) {
      const int col = col0 + wn + j * 16 + cl;
      #pragma unroll
      for (int r = 0; r < 4; ++r) {
        const int rl = wm + i * 16 + quad * 4 + r;
        if (tm * 128 + rl < ne) {
          const int tok = toks[rl];
          if (EPI == 0)
            Hout[(size_t)tok * N + col] = f2bf(acc[i][j][r] + bias[(size_t)e * N + col]);
          else
            Pp[(size_t)tok * N + col] = acc[i][j][r];
        }
      }
    }
}

// ---------------------------------------------------------------------------
// MFMA flash attention, split-bf16 (error ~1e-5: protects router decisions).
// grid = (S/64, H, B), block = 256 (4 waves; wave w owns q-rows w*16..w*16+15).
// ---------------------------------------------------------------------------
__global__ __launch_bounds__(256, 2) void attn_mfma_kernel(
    const u16* __restrict__ QKh, const u16* __restrict__ QKl,
    const u16* __restrict__ Vth, const u16* __restrict__ Vtl,
    const float* __restrict__ scale_w,
    float* __restrict__ AOf, u16* __restrict__ AOh, u16* __restrict__ AOl) {
  const int qt = blockIdx.x, h = blockIdx.y, b = blockIdx.z;
  __shared__ u16 Kh[64*64], Kl[64*64], Vh[64*64], Vl[64*64];   // 32 KB
  __shared__ u16 Ph[4][16*72], Pl[4][16*72];                   // 18.4 KB
  const int tid = threadIdx.x, lane = tid & 63, wave = tid >> 6;
  const int i15 = lane & 15, quad = lane >> 4;
  const floatx4 zero = {0.f, 0.f, 0.f, 0.f};

  short8 qh[2], ql[2];
  const size_t qrow = ((size_t)b * 1024 + qt * 64 + wave * 16 + i15) * 3072 + h * 64;
  #pragma unroll
  for (int kk = 0; kk < 2; ++kk) {
    qh[kk] = *(const short8*)&QKh[qrow + kk * 32 + quad * 8];
    ql[kk] = *(const short8*)&QKl[qrow + kk * 32 + quad * 8];
  }
  float dot = 0.f;
  #pragma unroll
  for (int kk = 0; kk < 2; ++kk)
    #pragma unroll
    for (int j = 0; j < 8; ++j) {
      const float sw = scale_w[h * 64 + kk * 32 + quad * 8 + j];
      dot += (bf2f((u16)qh[kk][j]) + bf2f((u16)ql[kk][j])) * sw;
    }
  dot += __shfl_xor(dot, 16);
  dot += __shfl_xor(dot, 32);
  const float g = 2.f * sigmoidf_(dot) * 0.125f;
  float stot[4];
  #pragma unroll
  for (int r = 0; r < 4; ++r) stot[r] = __shfl(g, (lane >> 4) * 4 + r);

  float m_r[4], l_r[4];
  floatx4 Of[4];
  #pragma unroll
  for (int r = 0; r < 4; ++r) { m_r[r] = -1e30f; l_r[r] = 0.f; }
  #pragma unroll
  for (int f = 0; f < 4; ++f) Of[f] = zero;
  u16* PhW = Ph[wave];
  u16* PlW = Pl[wave];

  const int sr = tid >> 3, sc = ((tid & 7) ^ ((tid >> 3) & 7)) * 8;
  for (int kt = 0; kt < 16; ++kt) {
    __syncthreads();
    #pragma unroll
    for (int p = 0; p < 2; ++p) {
      const int row = p * 32 + sr;
      const size_t off = (size_t)(p * 256 + wave * 64) * 16;
      const size_t kg = ((size_t)b * 1024 + kt * 64 + row) * 3072 + 1024 + h * 64 + sc;
      gload16(QKh + kg, (char*)Kh + off);
      gload16(QKl + kg, (char*)Kl + off);
      const size_t vg = ((size_t)(b * 16 + h) * 64 + row) * 1024 + kt * 64 + sc;
      gload16(Vth + vg, (char*)Vh + off);
      gload16(Vtl + vg, (char*)Vl + off);
    }
    __syncthreads();
    float pm[4][4];
    #pragma unroll
    for (int jn = 0; jn < 4; ++jn) {
      floatx4 a = zero;
      #pragma unroll
      for (int kk = 0; kk < 2; ++kk) {
        const int n = jn * 16 + i15;
        const int ch = ((kk * 4 + quad) ^ (n & 7)) * 8;
        const short8 bh = *(const short8*)&Kh[n * 64 + ch];
        const short8 bl = *(const short8*)&Kl[n * 64 + ch];
        a = __builtin_amdgcn_mfma_f32_16x16x32_bf16(qh[kk], bh, a, 0, 0, 0);
        a = __builtin_amdgcn_mfma_f32_16x16x32_bf16(ql[kk], bh, a, 0, 0, 0);
        a = __builtin_amdgcn_mfma_f32_16x16x32_bf16(qh[kk], bl, a, 0, 0, 0);
      }
      #pragma unroll
      for (int r = 0; r < 4; ++r) pm[jn][r] = a[r] * stot[r];
    }
    float alpha[4];
    #pragma unroll
    for (int r = 0; r < 4; ++r) {
      float mx = fmaxf(fmaxf(pm[0][r], pm[1][r]), fmaxf(pm[2][r], pm[3][r]));
      mx = fmaxf(mx, __shfl_xor(mx, 1));
      mx = fmaxf(mx, __shfl_xor(mx, 2));
      mx = fmaxf(mx, __shfl_xor(mx, 4));
      mx = fmaxf(mx, __shfl_xor(mx, 8));
      const float mn = fmaxf(m_r[r], mx);
      alpha[r] = expf(m_r[r] - mn);
      m_r[r] = mn;
      float rs = 0.f;
      #pragma unroll
      for (int jn = 0; jn < 4; ++jn) { pm[jn][r] = expf(pm[jn][r] - mn); rs += pm[jn][r]; }
      rs += __shfl_xor(rs, 1);
      rs += __shfl_xor(rs, 2);
      rs += __shfl_xor(rs, 4);
      rs += __shfl_xor(rs, 8);
      l_r[r] = l_r[r] * alpha[r] + rs;
    }
    #pragma unroll
    for (int f = 0; f < 4; ++f)
      #pragma unroll
      for (int r = 0; r < 4; ++r) Of[f][r] *= alpha[r];
    #pragma unroll
    for (int jn = 0; jn < 4; ++jn)
      #pragma unroll
      for (int r = 0; r < 4; ++r) {
        const int a = (quad * 4 + r) * 72 + jn * 16 + i15;
        const u16 hh = f2bf(pm[jn][r]);
        PhW[a] = hh;
        PlW[a] = f2bf(pm[jn][r] - bf2f(hh));
      }
    #pragma unroll
    for (int kk = 0; kk < 2; ++kk) {
      const short8 pah = *(const short8*)&PhW[i15 * 72 + kk * 32 + quad * 8];
      const short8 pal = *(const short8*)&PlW[i15 * 72 + kk * 32 + quad * 8];
      #pragma unroll
      for (int f = 0; f < 4; ++f) {
        const int d = f * 16 + i15;
        const int ch = ((kk * 4 + quad) ^ (d & 7)) * 8;
        const short8 vbh = *(const short8*)&Vh[d * 64 + ch];
        const short8 vbl = *(const short8*)&Vl[d * 64 + ch];
        Of[f] = __builtin_amdgcn_mfma_f32_16x16x32_bf16(pah, vbh, Of[f], 0, 0, 0);
        Of[f] = __builtin_amdgcn_mfma_f32_16x16x32_bf16(pal, vbh, Of[f], 0, 0, 0);
        Of[f] = __builtin_amdgcn_mfma_f32_16x16x32_bf16(pah, vbl, Of[f], 0, 0, 0);
      }
    }
  }
  float inv[4];
  #pragma unroll
  for (int r = 0; r < 4; ++r) inv[r] = 1.f / l_r[r];
  #pragma unroll
  for (int f = 0; f < 4; ++f)
    #pragma unroll
    for (int r = 0; r < 4; ++r) {
      const size_t row = (size_t)b * 1024 + qt * 64 + wave * 16 + quad * 4 + r;
      const int col = h * 64 + f * 16 + i15;
      const float val = Of[f][r] * inv[r];
      AOf[row * 1024 + col] = val;
      const u16 hh = f2bf(val);
      AOh[row * 1024 + col] = hh;
      AOl[row * 1024 + col] = f2bf(val - bf2f(hh));
    }
}

// ---------------------------------------------------------------------------
// x = LN(a + b) * g + beta  -> fp32 out (+ optional bf16 copy for MFMA input)
// ---------------------------------------------------------------------------
template<bool BF>
__global__ __launch_bounds__(256) void ln_add_kernel(
    const float* __restrict__ A, const float* __restrict__ Bp,
    const float* __restrict__ g, const float* __restrict__ beta,
    float* __restrict__ outf, u16* __restrict__ outh) {
  int t = blockIdx.x, tid = threadIdx.x;
  const float* a = A + (size_t)t * DMODEL;
  const float* b = Bp + (size_t)t * DMODEL;
  float v[4]; float s = 0.f;
  #pragma unroll
  for (int i = 0; i < 4; ++i) { int d = tid + i*256; v[i] = a[d] + b[d]; s += v[i]; }
  s = blockReduceSum256(s);
  float mean = s * (1.f/1024.f);
  float q = 0.f;
  #pragma unroll
  for (int i = 0; i < 4; ++i) { float df = v[i]-mean; q += df*df; }
  q = blockReduceSum256(q);
  float rstd = rsqrtf(q*(1.f/1024.f) + 1e-5f);
  #pragma unroll
  for (int i = 0; i < 4; ++i) {
    int d = tid + i*256;
    float val = (v[i]-mean)*rstd*g[d] + beta[d];
    outf[(size_t)t*DMODEL + d] = val;
    if (BF) outh[(size_t)t*DMODEL + d] = f2bf(val);
  }
}

// ---------------------------------------------------------------------------
// Final fused kernel: y = (p0+p1 + b2[e])*rs[e] + x ; out = LN(x + y, n2)
// ---------------------------------------------------------------------------
__global__ __launch_bounds__(256) void ln_final_kernel(
    const float* __restrict__ X, const float* __restrict__ P0,
    const float* __restrict__ P1, const float* __restrict__ B2,
    const float* __restrict__ rsv, const int* __restrict__ e_sel,
    const float* __restrict__ g, const float* __restrict__ beta,
    float* __restrict__ out) {
  int t = blockIdx.x, tid = threadIdx.x;
  const int e = e_sel[t];
  const float rse = rsv[e];
  const float* b2e = B2 + (size_t)e * DMODEL;
  float v[4]; float s = 0.f;
  #pragma unroll
  for (int i = 0; i < 4; ++i) {
    int d = tid + i*256;
    const size_t idx = (size_t)t * DMODEL + d;
    const float xv = X[idx];
    const float yv = (P0[idx] + P1[idx] + b2e[d]) * rse + xv;
    v[i] = xv + yv;
    s += v[i];
  }
  s = blockReduceSum256(s);
  float mean = s * (1.f/1024.f);
  float q = 0.f;
  #pragma unroll
  for (int i = 0; i < 4; ++i) { float df = v[i]-mean; q += df*df; }
  q = blockReduceSum256(q);
  float rstd = rsqrtf(q*(1.f/1024.f) + 1e-5f);
  #pragma unroll
  for (int i = 0; i < 4; ++i) {
    int d = tid + i*256;
    out[(size_t)t*DMODEL + d] = (v[i]-mean)*rstd*g[d] + beta[d];
  }
}

// ---------------------------------------------------------------------------
// MoE router (fp32): e_sel = max index of top-2 logits.
// ---------------------------------------------------------------------------
__global__ __launch_bounds__(256) void moe_gate_kernel(
    const float* __restrict__ X, const float* __restrict__ gw,
    const float* __restrict__ gb, int* __restrict__ e_sel) {
  int wave = threadIdx.x >> 6, lane = threadIdx.x & 63;
  int token = blockIdx.x * 4 + wave;
  const float* x = X + (size_t)token * DMODEL;
  float acc[NEXP] = {};
  for (int d = lane; d < DMODEL; d += 64) {
    float xv = x[d];
    const float* gr = gw + (size_t)d * NEXP;
    #pragma unroll
    for (int e = 0; e < NEXP; ++e) acc[e] += xv * gr[e];
  }
  #pragma unroll
  for (int e = 0; e < NEXP; ++e) {
    #pragma unroll
    for (int off = 32; off; off >>= 1) acc[e] += __shfl_down(acc[e], off);
  }
  if (lane == 0) {
    float lg[NEXP];
    #pragma unroll
    for (int e = 0; e < NEXP; ++e) lg[e] = acc[e] + gb[e];
    int i1 = 0;
    for (int e = 1; e < NEXP; ++e) if (lg[e] > lg[i1]) i1 = e;
    int i2 = -1;
    for (int e = 0; e < NEXP; ++e) {
      if (e == i1) continue;
      if (i2 < 0 || lg[e] > lg[i2]) i2 = e;
    }
    e_sel[token] = (i1 > i2) ? i1 : i2;
  }
}

__global__ __launch_bounds__(256) void moe_group_kernel(
    const int* __restrict__ e_sel, int* __restrict__ perm,
    int* __restrict__ g_offs, int* __restrict__ g_counts) {
  __shared__ int cnt[NEXP], offs[NEXP], cur[NEXP];
  int tid = threadIdx.x;
  if (tid < NEXP) cnt[tid] = 0;
  __syncthreads();
  for (int t = tid; t < TOK; t += 256) atomicAdd(&cnt[e_sel[t]], 1);
  __syncthreads();
  if (tid == 0) {
    int run = 0;
    for (int e = 0; e < NEXP; ++e) { offs[e] = run; cur[e] = run; run += cnt[e]; }
  }
  __syncthreads();
  if (tid < NEXP) { g_offs[tid] = offs[tid]; g_counts[tid] = cnt[tid]; }
  for (int t = tid; t < TOK; t += 256) {
    int pos = atomicAdd(&cur[e_sel[t]], 1);
    perm[pos] = t;
  }
}

// LN over DFF (per selected expert) + exact-erf GELU, in place on bf16 h.
__global__ __launch_bounds__(256) void moe_ln_gelu_kernel(
    u16* __restrict__ H, const float* __restrict__ ln_g,
    const float* __restrict__ ln_b, const int* __restrict__ e_sel) {
  int t = blockIdx.x, tid = threadIdx.x;
  int e = e_sel[t];
  u16* h = H + (size_t)t * DFFN;
  float v[16]; float s = 0.f;
  #pragma unroll
  for (int i = 0; i < 16; ++i) { v[i] = bf2f(h[tid + i*256]); s += v[i]; }
  s = blockReduceSum256(s);
  float mean = s * (1.f/4096.f);
  float q = 0.f;
  #pragma unroll
  for (int i = 0; i < 16; ++i) { float df = v[i]-mean; q += df*df; }
  q = blockReduceSum256(q);
  float rstd = rsqrtf(q*(1.f/4096.f) + 1e-5f);
  const float* gg = ln_g + (size_t)e * DFFN;
  const float* bb = ln_b + (size_t)e * DFFN;
  #pragma unroll
  for (int i = 0; i < 16; ++i) {
    int d = tid + i*256;
    float x = (v[i]-mean)*rstd*gg[d] + bb[d];
    h[d] = f2bf(0.5f * x * (1.f + erff(x * 0.7071067811865475f)));
  }
}

// ---------------------------------------------------------------------------
extern "C" void kernel_launch(void* const* d_in, const int* in_sizes, int n_in,
                              void* d_out, int out_size, void* d_ws, size_t ws_size,
                              hipStream_t stream) {
  (void)in_sizes; (void)n_in; (void)out_size; (void)ws_size;
  const float* src    = (const float*)d_in[0];
  const float* qw     = (const float*)d_in[1];
  const float* kw     = (const float*)d_in[2];
  const float* vw     = (const float*)d_in[3];
  const float* ow     = (const float*)d_in[4];
  const float* gate_w = (const float*)d_in[5];
  const float* gate_b = (const float*)d_in[6];
  const float* scale_w= (const float*)d_in[7];
  const float* n1_g   = (const float*)d_in[8];
  const float* n1_b   = (const float*)d_in[9];
  const float* n2_g   = (const float*)d_in[10];
  const float* n2_b   = (const float*)d_in[11];
  const float* mgw    = (const float*)d_in[12];
  const float* mgb    = (const float*)d_in[13];
  const float* w1     = (const float*)d_in[14];
  const float* b1     = (const float*)d_in[15];
  const float* ln_g   = (const float*)d_in[16];
  const float* ln_b   = (const float*)d_in[17];
  const float* w2     = (const float*)d_in[18];
  const float* b2     = (const float*)d_in[19];
  const float* rs     = (const float*)d_in[20];

  char* ws = (char*)d_ws;
  const size_t MB = 1024 * 1024;
  // timeline-packed buffers (lifetimes annotated)
  u16*   qkv_hi = (u16*)(ws + 0*MB);    // 12 MB  [dead after attn]
  u16*   qkv_lo = (u16*)(ws + 12*MB);   // 12 MB
  u16*   Wt3_hi = (u16*)(ws + 24*MB);   // 6 MB   [QKV weights / reused per GEMM]
  u16*   Wt3_lo = (u16*)(ws + 30*MB);   // 6 MB
  u16*   Vt_hi  = (u16*)(ws + 36*MB);   // 4 MB   [written by QKV gemm; dead after attn]
  u16*   Vt_lo  = (u16*)(ws + 40*MB);   // 4 MB
  u16*   src_hi = (u16*)(ws + 44*MB);   // 4 MB   [dead after QKV gemm]
  u16*   src_lo = (u16*)(ws + 48*MB);   // 4 MB
  float* ao     = (float*)(ws + 44*MB); // 8 MB   [written by attn, after src dead]
  u16*   ao_hi  = (u16*)(ws + 52*MB);   // 4 MB
  u16*   ao_lo  = (u16*)(ws + 56*MB);   // 4 MB
  u16*   gb_hi  = (u16*)(ws + 60*MB);   // 4 MB   [dead after ow gemm]
  u16*   gb_lo  = (u16*)(ws + 64*MB);   // 4 MB
  float* proj   = (float*)(ws + 0*MB);  // 8 MB   [qkv dead by then; dead after ln1]
  float* x      = (float*)(ws + 8*MB);  // 8 MB   [persists]
  u16*   x_hi   = (u16*)(ws + 16*MB);   // 4 MB   [dead after FFN1]
  u16*   WtA    = (u16*)(ws + 24*MB);   // 32 MB  [MoE weights; Wt3/Vt/ao dead]
  u16*   h      = (u16*)(ws + 56*MB);   // 16 MB  [ao_lo/gb dead]
  float* p0     = (float*)(ws + 0*MB);  // 8 MB   [FFN2 partial; proj dead]
  float* p1     = (float*)(ws + 72*MB); // 8 MB
  int*   e_sel  = (int*)(ws + 80*MB);
  int*   perm   = e_sel + TOK;
  int*   offs   = perm + TOK;
  int*   cnts   = offs + NEXP;

  dim3 blk(256);
  split_kernel<<<2048, blk, 0, stream>>>(src, src_hi, src_lo);

  // fused QKV: Wt3[3072][1024] <- qw|kw|vw (single conversion launch), then
  // one 2048x3072x1024 split GEMM; V columns written directly transposed.
  wt3_conv_kernel<<<dim3(32,1,96), blk, 0, stream>>>(qw, kw, vw, Wt3_hi, Wt3_lo);
  gemm_split_kernel<2,128><<<dim3(24,16), blk, 0, stream>>>(src_hi, src_lo, Wt3_hi, Wt3_lo,
      nullptr, nullptr, nullptr, qkv_hi, qkv_lo, Vt_hi, Vt_lo, TOK, 3072, DMODEL);

  // MFMA flash attention (split-bf16, dynamic scale gate)
  attn_mfma_kernel<<<dim3(16, NHEAD, 2), blk, 0, stream>>>(
      qkv_hi, qkv_lo, Vt_hi, Vt_lo, scale_w, ao, ao_hi, ao_lo);

  // gate = sigmoid(ao @ gate_w + gate_b); gbuf = ao * gate (split output)
  wt_conv_kernel<true><<<dim3(32,32,1), blk, 0, stream>>>(gate_w, Wt3_hi, Wt3_lo, DMODEL, DMODEL);
  gemm_split_kernel<1,64><<<dim3(16,16), blk, 0, stream>>>(ao_hi, ao_lo, Wt3_hi, Wt3_lo,
      gate_b, ao, nullptr, gb_hi, gb_lo, nullptr, nullptr, TOK, DMODEL, DMODEL);
  // proj = gbuf @ ow
  wt_conv_kernel<true><<<dim3(32,32,1), blk, 0, stream>>>(ow, Wt3_hi, Wt3_lo, DMODEL, DMODEL);
  gemm_split_kernel<0,64><<<dim3(16,16), blk, 0, stream>>>(gb_hi, gb_lo, Wt3_hi, Wt3_lo,
      nullptr, nullptr, proj, nullptr, nullptr, nullptr, nullptr, TOK, DMODEL, DMODEL);

  // x = LN(src + proj); bf16 copy for MoE A-side
  ln_add_kernel<true><<<TOK, blk, 0, stream>>>(src, proj, n1_g, n1_b, x, x_hi);

  // router (fp32) + grouping
  moe_gate_kernel<<<TOK/4, blk, 0, stream>>>(x, mgw, mgb, e_sel);
  moe_group_kernel<<<1, blk, 0, stream>>>(e_sel, perm, offs, cnts);

  // FFN1 in two expert-chunks (WtA = 32 MB holds 4 experts)
  for (int c = 0; c < 2; ++c) {
    wt_conv_kernel<false><<<dim3(DFFN/32, DMODEL/32, 4), blk, 0, stream>>>(
        w1 + (size_t)c*4*DMODEL*DFFN, WtA, nullptr, DMODEL, DFFN);
    gemm_moe_kernel<0,128><<<dim3(DFFN/128, 16, 4), blk, 0, stream>>>(
        x_hi, WtA, b1, perm, offs, cnts, h, nullptr, nullptr, DFFN, DMODEL, c*4);
  }
  moe_ln_gelu_kernel<<<TOK, blk, 0, stream>>>(h, ln_g, ln_b, e_sel);
  // FFN2 in two expert-chunks, 2-way split-K (z = ez + 4*ks) -> p0/p1
  for (int c = 0; c < 2; ++c) {
    wt_conv_kernel<false><<<dim3(DMODEL/32, DFFN/32, 4), blk, 0, stream>>>(
        w2 + (size_t)c*4*DFFN*DMODEL, WtA, nullptr, DFFN, DMODEL);
    gemm_moe_kernel<1,64><<<dim3(DMODEL/64, 16, 8), blk, 0, stream>>>(
        h, WtA, nullptr, perm, offs, cnts, nullptr, p0, p1, DMODEL, DFFN, c*4);
  }
  // out = LN(x + ((p0+p1+b2[e])*rs[e] + x), n2)
  ln_final_kernel<<<TOK, blk, 0, stream>>>(x, p0, p1, b2, rs, e_sel, n2_g, n2_b, (float*)d_out);
}

// Round 2
// 713.663 us; speedup vs baseline: 1.0176x; 1.0176x over previous
//
#include <hip/hip_runtime.h>
#include <math.h>

// Problem constants (fixed by the reference)
#define TOK    2048      // B*S
#define DMODEL 1024
#define NHEAD  16
#define HDIM   64
#define NEXP   8
#define DFFN   4096

typedef unsigned short u16;
typedef __attribute__((ext_vector_type(8))) short short8;   // 8 bf16 (4 VGPRs)
typedef __attribute__((ext_vector_type(4))) float floatx4;  // MFMA C/D

__device__ __forceinline__ float sigmoidf_(float x) { return 1.f / (1.f + __expf(-x)); }

__device__ __forceinline__ u16 f2bf(float f) {               // RNE fp32->bf16
  union { float f; unsigned u; } v; v.f = f;
  unsigned r = v.u + 0x7FFFu + ((v.u >> 16) & 1u);
  return (u16)(r >> 16);
}
__device__ __forceinline__ float bf2f(u16 h) {
  union { unsigned u; float f; } v; v.u = ((unsigned)h) << 16; return v.f;
}

// async global->LDS, 16B per lane; LDS dest = wave-uniform base + lane*16
__device__ __forceinline__ void gload16(const void* g, void* l) {
  __builtin_amdgcn_global_load_lds((const __attribute__((address_space(1))) void*)g,
                                   (__attribute__((address_space(3))) void*)l, 16, 0, 0);
}

// block = 256 threads (4 waves). Broadcast result to all threads.
__device__ __forceinline__ float blockReduceSum256(float val) {
  __shared__ float ws_[4];
  #pragma unroll
  for (int off = 32; off; off >>= 1) val += __shfl_down(val, off);
  int lane = threadIdx.x & 63, w = threadIdx.x >> 6;
  if (lane == 0) ws_[w] = val;
  __syncthreads();
  float r = ws_[0] + ws_[1] + ws_[2] + ws_[3];
  __syncthreads();
  return r;
}

// ---------------------------------------------------------------------------
// fp32 -> (hi, lo) bf16 split, elementwise. grid = n/1024, 4 floats/thread.
// ---------------------------------------------------------------------------
__global__ __launch_bounds__(256) void split_kernel(
    const float* __restrict__ X, u16* __restrict__ Hi, u16* __restrict__ Lo) {
  const int i = blockIdx.x * 256 + threadIdx.x;
  const float4 v = ((const float4*)X)[i];
  const float f[4] = {v.x, v.y, v.z, v.w};
  union { u16 s[4]; uint2 u; } h, l;
  #pragma unroll
  for (int j = 0; j < 4; ++j) {
    h.s[j] = f2bf(f[j]);
    l.s[j] = f2bf(f[j] - bf2f(h.s[j]));
  }
  ((uint2*)Hi)[i] = h.u;
  ((uint2*)Lo)[i] = l.u;
}

// ---------------------------------------------------------------------------
// Weight convert+transpose: W[K][N] fp32 -> Wt_hi[N][K] bf16 (+ optional lo).
// blockIdx.z = batch (expert); strides K*N. 32x32 LDS tile.
// ---------------------------------------------------------------------------
template<bool LO>
__global__ __launch_bounds__(256) void wt_conv_kernel(
    const float* __restrict__ W, u16* __restrict__ Whi, u16* __restrict__ Wlo,
    int K, int N) {
  const size_t z = blockIdx.z;
  W   += z * (size_t)K * N;
  Whi += z * (size_t)K * N;
  if (LO) Wlo += z * (size_t)K * N;
  __shared__ float tile[32][33];
  const int n0 = blockIdx.x * 32, k0 = blockIdx.y * 32;
  const int r = threadIdx.x >> 3, c4 = (threadIdx.x & 7) * 4;
  const float4 v = *(const float4*)&W[(size_t)(k0 + r) * N + n0 + c4];
  tile[r][c4+0] = v.x; tile[r][c4+1] = v.y; tile[r][c4+2] = v.z; tile[r][c4+3] = v.w;
  __syncthreads();
  union { u16 s[4]; uint2 u; } h, l;
  #pragma unroll
  for (int j = 0; j < 4; ++j) {
    const float f = tile[c4 + j][r];
    h.s[j] = f2bf(f);
    if (LO) l.s[j] = f2bf(f - bf2f(h.s[j]));
  }
  *(uint2*)&Whi[(size_t)(n0 + r) * K + k0 + c4] = h.u;
  if (LO) *(uint2*)&Wlo[(size_t)(n0 + r) * K + k0 + c4] = l.u;
}

// Fused QKV weight conversion: z selects {qw, kw, vw} (32 z-slices each).
__global__ __launch_bounds__(256) void wt3_conv_kernel(
    const float* __restrict__ Q, const float* __restrict__ Kw,
    const float* __restrict__ V, u16* __restrict__ Whi, u16* __restrict__ Wlo) {
  const int zz = blockIdx.z >> 5;              // 0,1,2
  const float* W = (zz == 0) ? Q : (zz == 1) ? Kw : V;
  u16* Whi_ = Whi + (size_t)zz * DMODEL * DMODEL;
  u16* Wlo_ = Wlo + (size_t)zz * DMODEL * DMODEL;
  __shared__ float tile[32][33];
  const int n0 = blockIdx.x * 32, k0 = (blockIdx.z & 31) * 32;
  const int r = threadIdx.x >> 3, c4 = (threadIdx.x & 7) * 4;
  const float4 v = *(const float4*)&W[(size_t)(k0 + r) * DMODEL + n0 + c4];
  tile[r][c4+0] = v.x; tile[r][c4+1] = v.y; tile[r][c4+2] = v.z; tile[r][c4+3] = v.w;
  __syncthreads();
  union { u16 s[4]; uint2 u; } h, l;
  #pragma unroll
  for (int j = 0; j < 4; ++j) {
    const float f = tile[c4 + j][r];
    h.s[j] = f2bf(f);
    l.s[j] = f2bf(f - bf2f(h.s[j]));
  }
  *(uint2*)&Whi_[(size_t)(n0 + r) * DMODEL + k0 + c4] = h.u;
  *(uint2*)&Wlo_[(size_t)(n0 + r) * DMODEL + k0 + c4] = l.u;
}

// ---------------------------------------------------------------------------
// Split-precision bf16 MFMA GEMM: C[M,N] = A[M,K] @ W[K,N].
// A as (Ahi,Alo) bf16 [M][K]; W transposed (Whi,Wlo) bf16 [N][K].
// acc += Ah*Wh + Al*Wh + Ah*Wl  (error ~2^-18, protects MoE routing).
// Tile 128(M) x TN(N), BK=64, 4 waves 2x2 (wave tile 64 x TN/2), 16x16x32 MFMA.
// LDS chunk-swizzle: chunk c of row m holds global k-chunk (c ^ (m&7)).
// EPI 0: Cf = acc (fp32).
// EPI 1: g = sigmoid(acc+bias[n])*mul[m,n] -> Chi/Clo split.
// EPI 2: QKV path. cols < 2048 (Q,K): Chi/Clo = split(acc) row-major.
//        cols >= 2048 (V): store transposed into Vt[bh][d][tok] hi/lo
//        (4 acc rows = 4 consecutive tokens -> packed 8B store).
// ---------------------------------------------------------------------------
template<int EPI, int TN>
__global__ __launch_bounds__(256, TN == 64 ? 3 : 2) void gemm_split_kernel(
    const u16* __restrict__ Ahi, const u16* __restrict__ Alo,
    const u16* __restrict__ Whi, const u16* __restrict__ Wlo,
    const float* __restrict__ bias, const float* __restrict__ mul,
    float* __restrict__ Cf, u16* __restrict__ Chi, u16* __restrict__ Clo,
    u16* __restrict__ Vth, u16* __restrict__ Vtl,
    int M, int N, int K) {
  constexpr int NF = TN / 32;                    // B n-frags per wave (2 or 4)
  __shared__ u16 Ah[128*64], Al[128*64], Bh[TN*64], Bl[TN*64];
  const int tid = threadIdx.x;
  const int lane = tid & 63, wave = tid >> 6;
  const int row0 = blockIdx.y * 128, col0 = blockIdx.x * TN;
  const int wm = (wave & 1) * 64, wn = (wave >> 1) * (TN / 2);
  const int mr = tid >> 3;                       // staging row 0..31 (+p*32)
  const int ksrc = (tid & 7) ^ ((tid >> 3) & 7); // swizzled source k-chunk
  const floatx4 zero = {0.f, 0.f, 0.f, 0.f};
  floatx4 acc[4][NF];
  #pragma unroll
  for (int i = 0; i < 4; ++i)
    #pragma unroll
    for (int j = 0; j < NF; ++j) acc[i][j] = zero;

  for (int k0 = 0; k0 < K; k0 += 64) {
    __syncthreads();
    #pragma unroll
    for (int p = 0; p < 4; ++p) {               // A: 128 rows
      const size_t ga = (size_t)(row0 + p * 32 + mr) * K + (k0 + ksrc * 8);
      const size_t off = (size_t)(p * 256 + wave * 64) * 16;
      gload16(Ahi + ga, (char*)Ah + off);
      gload16(Alo + ga, (char*)Al + off);
    }
    #pragma unroll
    for (int p = 0; p < NF; ++p) {              // B: TN rows
      const size_t gb = (size_t)(col0 + p * 32 + mr) * K + (k0 + ksrc * 8);
      const size_t off = (size_t)(p * 256 + wave * 64) * 16;
      gload16(Whi + gb, (char*)Bh + off);
      gload16(Wlo + gb, (char*)Bl + off);
    }
    __syncthreads();
    #pragma unroll
    for (int kk = 0; kk < 2; ++kk) {
      short8 ah[4], al[4], bh[NF], bl[NF];
      #pragma unroll
      for (int i = 0; i < 4; ++i) {
        const int ml = wm + i * 16 + (lane & 15);
        const int cm = (kk * 4 + (lane >> 4)) ^ (ml & 7);
        ah[i] = *(const short8*)&Ah[ml * 64 + cm * 8];
        al[i] = *(const short8*)&Al[ml * 64 + cm * 8];
      }
      #pragma unroll
      for (int j = 0; j < NF; ++j) {
        const int nl = wn + j * 16 + (lane & 15);
        const int cn = (kk * 4 + (lane >> 4)) ^ (nl & 7);
        bh[j] = *(const short8*)&Bh[nl * 64 + cn * 8];
        bl[j] = *(const short8*)&Bl[nl * 64 + cn * 8];
      }
      #pragma unroll
      for (int i = 0; i < 4; ++i)
        #pragma unroll
        for (int j = 0; j < NF; ++j) {
          acc[i][j] = __builtin_amdgcn_mfma_f32_16x16x32_bf16(ah[i], bh[j], acc[i][j], 0, 0, 0);
          acc[i][j] = __builtin_amdgcn_mfma_f32_16x16x32_bf16(al[i], bh[j], acc[i][j], 0, 0, 0);
          acc[i][j] = __builtin_amdgcn_mfma_f32_16x16x32_bf16(ah[i], bl[j], acc[i][j], 0, 0, 0);
        }
    }
  }
  const int cl = lane & 15, quad = lane >> 4;
  if (EPI == 2 && col0 >= 2048) {
    // V region: transposed store into Vt[bh][d][tok] (hi/lo), 8B packed.
    #pragma unroll
    for (int i = 0; i < 4; ++i)
      #pragma unroll
      for (int j = 0; j < NF; ++j) {
        const int dg = col0 + wn + j * 16 + cl - 2048;
        const int bh_ = dg >> 6, d = dg & 63;
        const int row = row0 + wm + i * 16 + quad * 4;   // +r, 4 consecutive toks
        const int b = row >> 10, t0 = row & 1023;
        union { u16 s[4]; uint2 u; } hh, ll;
        #pragma unroll
        for (int r = 0; r < 4; ++r) {
          const float v = acc[i][j][r];
          hh.s[r] = f2bf(v);
          ll.s[r] = f2bf(v - bf2f(hh.s[r]));
        }
        const size_t base = ((size_t)(b * 16 + bh_) * 64 + d) * 1024 + t0;
        *(uint2*)&Vth[base] = hh.u;
        *(uint2*)&Vtl[base] = ll.u;
      }
    return;
  }
  #pragma unroll
  for (int i = 0; i < 4; ++i)
    #pragma unroll
    for (int j = 0; j < NF; ++j) {
      const int col = col0 + wn + j * 16 + cl;
      #pragma unroll
      for (int r = 0; r < 4; ++r) {
        const int row = row0 + wm + i * 16 + quad * 4 + r;
        const float v = acc[i][j][r];
        if (EPI == 0) {
          Cf[(size_t)row * N + col] = v;
        } else if (EPI == 1) {
          const float s = sigmoidf_(v + bias[col]);
          const float g = s * mul[(size_t)row * N + col];
          const u16 hh = f2bf(g);
          Chi[(size_t)row * N + col] = hh;
          Clo[(size_t)row * N + col] = f2bf(g - bf2f(hh));
        } else {
          const u16 hh = f2bf(v);
          Chi[(size_t)row * N + col] = hh;
          Clo[(size_t)row * N + col] = f2bf(v - bf2f(hh));
        }
      }
    }
}

// ---------------------------------------------------------------------------
// Grouped MoE GEMM, plain bf16 MFMA. Tile 128(M) x TN(N), 4 waves 2x2.
// EPI 0 (ffn1): z = local expert (4); full K. Hout = bf16(acc + bias[e][n]).
// EPI 1 (ffn2): z = ez + 4*ks (8): 2-way split-K; P[ks][tok*N+col] = acc fp32.
// ---------------------------------------------------------------------------
template<int EPI, int TN>
__global__ __launch_bounds__(256, TN == 64 ? 4 : 3) void gemm_moe_kernel(
    const u16* __restrict__ A, const u16* __restrict__ Wt,
    const float* __restrict__ bias,
    const int* __restrict__ perm, const int* __restrict__ offs,
    const int* __restrict__ counts,
    u16* __restrict__ Hout, float* __restrict__ P0, float* __restrict__ P1,
    int N, int K, int e_base) {
  constexpr int NF = TN / 32;
  const int z = blockIdx.z;
  const int ez = (EPI == 0) ? z : (z & 3);
  const int ks = (EPI == 0) ? 0 : (z >> 2);
  const int e = e_base + ez;
  const int ne = counts[e];
  const int tm = blockIdx.y;
  if (tm * 128 >= ne) return;
  const int kbeg = (EPI == 0) ? 0 : ks * (K >> 1);
  const int kend = (EPI == 0) ? K : kbeg + (K >> 1);
  __shared__ u16 As_[128*64], Bs_[TN*64];
  __shared__ int toks[128];
  const int tid = threadIdx.x;
  if (tid < 128) {
    const int idx = tm * 128 + tid;
    toks[tid] = perm[offs[e] + (idx < ne ? idx : 0)];
  }
  __syncthreads();
  const int lane = tid & 63, wave = tid >> 6;
  const int wm = (wave & 1) * 64, wn = (wave >> 1) * (TN / 2);
  const int mr = tid >> 3;
  const int ksrc = (tid & 7) ^ ((tid >> 3) & 7);
  size_t abase[4];
  #pragma unroll
  for (int p = 0; p < 4; ++p) abase[p] = (size_t)toks[p * 32 + mr] * K;
  const u16* We = Wt + (size_t)ez * N * K;
  const int col0 = blockIdx.x * TN;
  const floatx4 zero = {0.f, 0.f, 0.f, 0.f};
  floatx4 acc[4][NF];
  #pragma unroll
  for (int i = 0; i < 4; ++i)
    #pragma unroll
    for (int j = 0; j < NF; ++j) acc[i][j] = zero;

  for (int k0 = kbeg; k0 < kend; k0 += 64) {
    __syncthreads();
    #pragma unroll
    for (int p = 0; p < 4; ++p) {
      const size_t off = (size_t)(p * 256 + wave * 64) * 16;
      gload16(A + abase[p] + (k0 + ksrc * 8), (char*)As_ + off);
    }
    #pragma unroll
    for (int p = 0; p < NF; ++p) {
      const size_t off = (size_t)(p * 256 + wave * 64) * 16;
      gload16(We + (size_t)(col0 + p * 32 + mr) * K + (k0 + ksrc * 8), (char*)Bs_ + off);
    }
    __syncthreads();
    #pragma unroll
    for (int kk = 0; kk < 2; ++kk) {
      short8 a[4], b[NF];
      #pragma unroll
      for (int i = 0; i < 4; ++i) {
        const int ml = wm + i * 16 + (lane & 15);
        const int cm = (kk * 4 + (lane >> 4)) ^ (ml & 7);
        a[i] = *(const short8*)&As_[ml * 64 + cm * 8];
      }
      #pragma unroll
      for (int j = 0; j < NF; ++j) {
        const int nl = wn + j * 16 + (lane & 15);
        const int cn = (kk * 4 + (lane >> 4)) ^ (nl & 7);
        b[j] = *(const short8*)&Bs_[nl * 64 + cn * 8];
      }
      #pragma unroll
      for (int i = 0; i < 4; ++i)
        #pragma unroll
        for (int j = 0; j < NF; ++j)
          acc[i][j] = __builtin_amdgcn_mfma_f32_16x16x32_bf16(a[i], b[j], acc[i][j], 0, 0, 0);
    }
  }
  const int cl = lane & 15, quad = lane >> 4;
  float* Pp = (EPI == 1) ? (ks ? P1 : P0) : nullptr;
  #pragma unroll
  for (int i = 0; i < 4; ++i)
    #pragma unroll
    for (int j = 0; j < NF; ++j) {
      const int col = col0 + wn + j * 16 + cl;
      #pragma unroll
      for (int r = 0; r < 4; ++r) {
        const int rl = wm + i * 16 + quad * 4 + r;
        if (tm * 128 + rl < ne) {
          const int tok = toks[rl];
          if (EPI == 0)
            Hout[(size_t)tok * N + col] = f2bf(acc[i][j][r] + bias[(size_t)e * N + col]);
          else
            Pp[(size_t)tok * N + col] = acc[i][j][r];
        }
      }
    }
}

// ---------------------------------------------------------------------------
// MFMA flash attention, split-bf16 (error ~1e-5: protects router decisions).
// grid = (S/128, H, B), block = 512 (8 waves; wave w owns q-rows w*16..w*16+15).
// 1 block/CU, 16 waves/CU. Per-wave P chunk (16x40) reused across kk halves
// (DS ops are in-order within a wave, so WAR across kk needs no barrier).
// ---------------------------------------------------------------------------
__global__ __launch_bounds__(512, 2) void attn_mfma_kernel(
    const u16* __restrict__ QKh, const u16* __restrict__ QKl,
    const u16* __restrict__ Vth, const u16* __restrict__ Vtl,
    const float* __restrict__ scale_w,
    float* __restrict__ AOf, u16* __restrict__ AOh, u16* __restrict__ AOl) {
  const int qt = blockIdx.x, h = blockIdx.y, b = blockIdx.z;
  __shared__ u16 Kh[64*64], Kl[64*64], Vh[64*64], Vl[64*64];   // 32 KB
  __shared__ u16 Ph[8][16*40], Pl[8][16*40];                   // 20 KB
  const int tid = threadIdx.x, lane = tid & 63, wave = tid >> 6;
  const int i15 = lane & 15, quad = lane >> 4;
  const floatx4 zero = {0.f, 0.f, 0.f, 0.f};

  short8 qh[2], ql[2];
  const size_t qrow = ((size_t)b * 1024 + qt * 128 + wave * 16 + i15) * 3072 + h * 64;
  #pragma unroll
  for (int kk = 0; kk < 2; ++kk) {
    qh[kk] = *(const short8*)&QKh[qrow + kk * 32 + quad * 8];
    ql[kk] = *(const short8*)&QKl[qrow + kk * 32 + quad * 8];
  }
  float dot = 0.f;
  #pragma unroll
  for (int kk = 0; kk < 2; ++kk)
    #pragma unroll
    for (int j = 0; j < 8; ++j) {
      const float sw = scale_w[h * 64 + kk * 32 + quad * 8 + j];
      dot += (bf2f((u16)qh[kk][j]) + bf2f((u16)ql[kk][j])) * sw;
    }
  dot += __shfl_xor(dot, 16);
  dot += __shfl_xor(dot, 32);
  const float g = 2.f * sigmoidf_(dot) * 0.125f;
  float stot[4];
  #pragma unroll
  for (int r = 0; r < 4; ++r) stot[r] = __shfl(g, (lane >> 4) * 4 + r);

  float m_r[4], l_r[4];
  floatx4 Of[4];
  #pragma unroll
  for (int r = 0; r < 4; ++r) { m_r[r] = -1e30f; l_r[r] = 0.f; }
  #pragma unroll
  for (int f = 0; f < 4; ++f) Of[f] = zero;
  u16* PhW = Ph[wave];
  u16* PlW = Pl[wave];

  const int sr = tid >> 3;                         // staging row 0..63
  const int sc = ((tid & 7) ^ (sr & 7)) * 8;       // swizzled source k-chunk
  for (int kt = 0; kt < 16; ++kt) {
    __syncthreads();
    {
      const size_t off = (size_t)wave * 1024;      // bytes; +lane*16 by HW
      const size_t kg = ((size_t)b * 1024 + kt * 64 + sr) * 3072 + 1024 + h * 64 + sc;
      gload16(QKh + kg, (char*)Kh + off);
      gload16(QKl + kg, (char*)Kl + off);
      const size_t vg = ((size_t)(b * 16 + h) * 64 + sr) * 1024 + kt * 64 + sc;
      gload16(Vth + vg, (char*)Vh + off);
      gload16(Vtl + vg, (char*)Vl + off);
    }
    __syncthreads();
    float pm[4][4];
    #pragma unroll
    for (int jn = 0; jn < 4; ++jn) {
      floatx4 a = zero;
      #pragma unroll
      for (int kk = 0; kk < 2; ++kk) {
        const int n = jn * 16 + i15;
        const int ch = ((kk * 4 + quad) ^ (n & 7)) * 8;
        const short8 bh = *(const short8*)&Kh[n * 64 + ch];
        const short8 bl = *(const short8*)&Kl[n * 64 + ch];
        a = __builtin_amdgcn_mfma_f32_16x16x32_bf16(qh[kk], bh, a, 0, 0, 0);
        a = __builtin_amdgcn_mfma_f32_16x16x32_bf16(ql[kk], bh, a, 0, 0, 0);
        a = __builtin_amdgcn_mfma_f32_16x16x32_bf16(qh[kk], bl, a, 0, 0, 0);
      }
      #pragma unroll
      for (int r = 0; r < 4; ++r) pm[jn][r] = a[r] * stot[r];
    }
    float alpha[4];
    #pragma unroll
    for (int r = 0; r < 4; ++r) {
      float mx = fmaxf(fmaxf(pm[0][r], pm[1][r]), fmaxf(pm[2][r], pm[3][r]));
      mx = fmaxf(mx, __shfl_xor(mx, 1));
      mx = fmaxf(mx, __shfl_xor(mx, 2));
      mx = fmaxf(mx, __shfl_xor(mx, 4));
      mx = fmaxf(mx, __shfl_xor(mx, 8));
      const float mn = fmaxf(m_r[r], mx);
      alpha[r] = __expf(m_r[r] - mn);
      m_r[r] = mn;
      float rs = 0.f;
      #pragma unroll
      for (int jn = 0; jn < 4; ++jn) { pm[jn][r] = __expf(pm[jn][r] - mn); rs += pm[jn][r]; }
      rs += __shfl_xor(rs, 1);
      rs += __shfl_xor(rs, 2);
      rs += __shfl_xor(rs, 4);
      rs += __shfl_xor(rs, 8);
      l_r[r] = l_r[r] * alpha[r] + rs;
    }
    #pragma unroll
    for (int f = 0; f < 4; ++f)
      #pragma unroll
      for (int r = 0; r < 4; ++r) Of[f][r] *= alpha[r];
    #pragma unroll
    for (int kk = 0; kk < 2; ++kk) {
      #pragma unroll
      for (int jj = 0; jj < 2; ++jj) {
        const int jn = kk * 2 + jj;
        #pragma unroll
        for (int r = 0; r < 4; ++r) {
          const int a = (quad * 4 + r) * 40 + jj * 16 + i15;
          const u16 hh = f2bf(pm[jn][r]);
          PhW[a] = hh;
          PlW[a] = f2bf(pm[jn][r] - bf2f(hh));
        }
      }
      const short8 pah = *(const short8*)&PhW[i15 * 40 + quad * 8];
      const short8 pal = *(const short8*)&PlW[i15 * 40 + quad * 8];
      #pragma unroll
      for (int f = 0; f < 4; ++f) {
        const int d = f * 16 + i15;
        const int ch = ((kk * 4 + quad) ^ (d & 7)) * 8;
        const short8 vbh = *(const short8*)&Vh[d * 64 + ch];
        const short8 vbl = *(const short8*)&Vl[d * 64 + ch];
        Of[f] = __builtin_amdgcn_mfma_f32_16x16x32_bf16(pah, vbh, Of[f], 0, 0, 0);
        Of[f] = __builtin_amdgcn_mfma_f32_16x16x32_bf16(pal, vbh, Of[f], 0, 0, 0);
        Of[f] = __builtin_amdgcn_mfma_f32_16x16x32_bf16(pah, vbl, Of[f], 0, 0, 0);
      }
    }
  }
  float inv[4];
  #pragma unroll
  for (int r = 0; r < 4; ++r) inv[r] = 1.f / l_r[r];
  #pragma unroll
  for (int f = 0; f < 4; ++f)
    #pragma unroll
    for (int r = 0; r < 4; ++r) {
      const size_t row = (size_t)b * 1024 + qt * 128 + wave * 16 + quad * 4 + r;
      const int col = h * 64 + f * 16 + i15;
      const float val = Of[f][r] * inv[r];
      AOf[row * 1024 + col] = val;
      const u16 hh = f2bf(val);
      AOh[row * 1024 + col] = hh;
      AOl[row * 1024 + col] = f2bf(val - bf2f(hh));
    }
}

// ---------------------------------------------------------------------------
// x = LN(a + b) * g + beta  -> fp32 out (+ optional bf16 copy for MFMA input)
// (scalar-strided loads kept: reduction order feeds the router — keep bit-stable)
// ---------------------------------------------------------------------------
template<bool BF>
__global__ __launch_bounds__(256) void ln_add_kernel(
    const float* __restrict__ A, const float* __restrict__ Bp,
    const float* __restrict__ g, const float* __restrict__ beta,
    float* __restrict__ outf, u16* __restrict__ outh) {
  int t = blockIdx.x, tid = threadIdx.x;
  const float* a = A + (size_t)t * DMODEL;
  const float* b = Bp + (size_t)t * DMODEL;
  float v[4]; float s = 0.f;
  #pragma unroll
  for (int i = 0; i < 4; ++i) { int d = tid + i*256; v[i] = a[d] + b[d]; s += v[i]; }
  s = blockReduceSum256(s);
  float mean = s * (1.f/1024.f);
  float q = 0.f;
  #pragma unroll
  for (int i = 0; i < 4; ++i) { float df = v[i]-mean; q += df*df; }
  q = blockReduceSum256(q);
  float rstd = rsqrtf(q*(1.f/1024.f) + 1e-5f);
  #pragma unroll
  for (int i = 0; i < 4; ++i) {
    int d = tid + i*256;
    float val = (v[i]-mean)*rstd*g[d] + beta[d];
    outf[(size_t)t*DMODEL + d] = val;
    if (BF) outh[(size_t)t*DMODEL + d] = f2bf(val);
  }
}

// ---------------------------------------------------------------------------
// Final fused kernel: y = (p0+p1 + b2[e])*rs[e] + x ; out = LN(x + y, n2)
// float4-vectorized (post-routing; reduction-order change harmless).
// ---------------------------------------------------------------------------
__global__ __launch_bounds__(256) void ln_final_kernel(
    const float* __restrict__ X, const float* __restrict__ P0,
    const float* __restrict__ P1, const float* __restrict__ B2,
    const float* __restrict__ rsv, const int* __restrict__ e_sel,
    const float* __restrict__ g, const float* __restrict__ beta,
    float* __restrict__ out) {
  int t = blockIdx.x, tid = threadIdx.x;
  const int e = e_sel[t];
  const float rse = rsv[e];
  const float* b2e = B2 + (size_t)e * DMODEL;
  const int d0 = tid * 4;
  const size_t base = (size_t)t * DMODEL + d0;
  const float4 xv = *(const float4*)&X[base];
  const float4 p0v = *(const float4*)&P0[base];
  const float4 p1v = *(const float4*)&P1[base];
  const float4 bv = *(const float4*)&b2e[d0];
  float v[4]; float s = 0.f;
  v[0] = 2.f*xv.x + (p0v.x + p1v.x + bv.x) * rse;
  v[1] = 2.f*xv.y + (p0v.y + p1v.y + bv.y) * rse;
  v[2] = 2.f*xv.z + (p0v.z + p1v.z + bv.z) * rse;
  v[3] = 2.f*xv.w + (p0v.w + p1v.w + bv.w) * rse;
  s = v[0] + v[1] + v[2] + v[3];
  s = blockReduceSum256(s);
  float mean = s * (1.f/1024.f);
  float q = 0.f;
  #pragma unroll
  for (int i = 0; i < 4; ++i) { float df = v[i]-mean; q += df*df; }
  q = blockReduceSum256(q);
  float rstd = rsqrtf(q*(1.f/1024.f) + 1e-5f);
  const float4 g4 = *(const float4*)&g[d0];
  const float4 be4 = *(const float4*)&beta[d0];
  float4 o;
  o.x = (v[0]-mean)*rstd*g4.x + be4.x;
  o.y = (v[1]-mean)*rstd*g4.y + be4.y;
  o.z = (v[2]-mean)*rstd*g4.z + be4.z;
  o.w = (v[3]-mean)*rstd*g4.w + be4.w;
  *(float4*)&out[base] = o;
}

// ---------------------------------------------------------------------------
// MoE router (fp32): e_sel = max index of top-2 logits.
// ---------------------------------------------------------------------------
__global__ __launch_bounds__(256) void moe_gate_kernel(
    const float* __restrict__ X, const float* __restrict__ gw,
    const float* __restrict__ gb, int* __restrict__ e_sel) {
  int wave = threadIdx.x >> 6, lane = threadIdx.x & 63;
  int token = blockIdx.x * 4 + wave;
  const float* x = X + (size_t)token * DMODEL;
  float acc[NEXP] = {};
  for (int d = lane; d < DMODEL; d += 64) {
    float xv = x[d];
    const float* gr = gw + (size_t)d * NEXP;
    #pragma unroll
    for (int e = 0; e < NEXP; ++e) acc[e] += xv * gr[e];
  }
  #pragma unroll
  for (int e = 0; e < NEXP; ++e) {
    #pragma unroll
    for (int off = 32; off; off >>= 1) acc[e] += __shfl_down(acc[e], off);
  }
  if (lane == 0) {
    float lg[NEXP];
    #pragma unroll
    for (int e = 0; e < NEXP; ++e) lg[e] = acc[e] + gb[e];
    int i1 = 0;
    for (int e = 1; e < NEXP; ++e) if (lg[e] > lg[i1]) i1 = e;
    int i2 = -1;
    for (int e = 0; e < NEXP; ++e) {
      if (e == i1) continue;
      if (i2 < 0 || lg[e] > lg[i2]) i2 = e;
    }
    e_sel[token] = (i1 > i2) ? i1 : i2;
  }
}

__global__ __launch_bounds__(256) void moe_group_kernel(
    const int* __restrict__ e_sel, int* __restrict__ perm,
    int* __restrict__ g_offs, int* __restrict__ g_counts) {
  __shared__ int cnt[NEXP], offs[NEXP], cur[NEXP];
  int tid = threadIdx.x;
  if (tid < NEXP) cnt[tid] = 0;
  __syncthreads();
  for (int t = tid; t < TOK; t += 256) atomicAdd(&cnt[e_sel[t]], 1);
  __syncthreads();
  if (tid == 0) {
    int run = 0;
    for (int e = 0; e < NEXP; ++e) { offs[e] = run; cur[e] = run; run += cnt[e]; }
  }
  __syncthreads();
  if (tid < NEXP) { g_offs[tid] = offs[tid]; g_counts[tid] = cnt[tid]; }
  for (int t = tid; t < TOK; t += 256) {
    int pos = atomicAdd(&cur[e_sel[t]], 1);
    perm[pos] = t;
  }
}

// LN over DFF (per selected expert) + exact-erf GELU, in place on bf16 h.
// Vectorized (post-routing; reduction-order change harmless).
__global__ __launch_bounds__(256) void moe_ln_gelu_kernel(
    u16* __restrict__ H, const float* __restrict__ ln_g,
    const float* __restrict__ ln_b, const int* __restrict__ e_sel) {
  int t = blockIdx.x, tid = threadIdx.x;
  int e = e_sel[t];
  u16* hp = H + (size_t)t * DFFN;
  float v[16]; float s = 0.f;
  #pragma unroll
  for (int i = 0; i < 4; ++i) {
    const int d = i * 1024 + tid * 4;
    union { uint2 u; u16 q[4]; } hv;
    hv.u = *(const uint2*)&hp[d];
    #pragma unroll
    for (int j = 0; j < 4; ++j) { v[i*4+j] = bf2f(hv.q[j]); s += v[i*4+j]; }
  }
  s = blockReduceSum256(s);
  float mean = s * (1.f/4096.f);
  float q = 0.f;
  #pragma unroll
  for (int i = 0; i < 16; ++i) { float df = v[i]-mean; q += df*df; }
  q = blockReduceSum256(q);
  float rstd = rsqrtf(q*(1.f/4096.f) + 1e-5f);
  const float* gg = ln_g + (size_t)e * DFFN;
  const float* bb = ln_b + (size_t)e * DFFN;
  #pragma unroll
  for (int i = 0; i < 4; ++i) {
    const int d = i * 1024 + tid * 4;
    const float4 g4 = *(const float4*)&gg[d];
    const float4 b4 = *(const float4*)&bb[d];
    const float gf[4] = {g4.x, g4.y, g4.z, g4.w};
    const float bf[4] = {b4.x, b4.y, b4.z, b4.w};
    union { uint2 u; u16 q[4]; } ov;
    #pragma unroll
    for (int j = 0; j < 4; ++j) {
      float xx = (v[i*4+j]-mean)*rstd*gf[j] + bf[j];
      ov.q[j] = f2bf(0.5f * xx * (1.f + erff(xx * 0.7071067811865475f)));
    }
    *(uint2*)&hp[d] = ov.u;
  }
}

// ---------------------------------------------------------------------------
extern "C" void kernel_launch(void* const* d_in, const int* in_sizes, int n_in,
                              void* d_out, int out_size, void* d_ws, size_t ws_size,
                              hipStream_t stream) {
  (void)in_sizes; (void)n_in; (void)out_size; (void)ws_size;
  const float* src    = (const float*)d_in[0];
  const float* qw     = (const float*)d_in[1];
  const float* kw     = (const float*)d_in[2];
  const float* vw     = (const float*)d_in[3];
  const float* ow     = (const float*)d_in[4];
  const float* gate_w = (const float*)d_in[5];
  const float* gate_b = (const float*)d_in[6];
  const float* scale_w= (const float*)d_in[7];
  const float* n1_g   = (const float*)d_in[8];
  const float* n1_b   = (const float*)d_in[9];
  const float* n2_g   = (const float*)d_in[10];
  const float* n2_b   = (const float*)d_in[11];
  const float* mgw    = (const float*)d_in[12];
  const float* mgb    = (const float*)d_in[13];
  const float* w1     = (const float*)d_in[14];
  const float* b1     = (const float*)d_in[15];
  const float* ln_g   = (const float*)d_in[16];
  const float* ln_b   = (const float*)d_in[17];
  const float* w2     = (const float*)d_in[18];
  const float* b2     = (const float*)d_in[19];
  const float* rs     = (const float*)d_in[20];

  char* ws = (char*)d_ws;
  const size_t MB = 1024 * 1024;
  // timeline-packed buffers (lifetimes annotated)
  u16*   qkv_hi = (u16*)(ws + 0*MB);    // 12 MB  [dead after attn]
  u16*   qkv_lo = (u16*)(ws + 12*MB);   // 12 MB
  u16*   Wt3_hi = (u16*)(ws + 24*MB);   // 6 MB   [QKV weights / reused per GEMM]
  u16*   Wt3_lo = (u16*)(ws + 30*MB);   // 6 MB
  u16*   Vt_hi  = (u16*)(ws + 36*MB);   // 4 MB   [written by QKV gemm; dead after attn]
  u16*   Vt_lo  = (u16*)(ws + 40*MB);   // 4 MB
  u16*   src_hi = (u16*)(ws + 44*MB);   // 4 MB   [dead after QKV gemm]
  u16*   src_lo = (u16*)(ws + 48*MB);   // 4 MB
  float* ao     = (float*)(ws + 44*MB); // 8 MB   [written by attn, after src dead]
  u16*   ao_hi  = (u16*)(ws + 52*MB);   // 4 MB
  u16*   ao_lo  = (u16*)(ws + 56*MB);   // 4 MB
  u16*   gb_hi  = (u16*)(ws + 60*MB);   // 4 MB   [dead after ow gemm]
  u16*   gb_lo  = (u16*)(ws + 64*MB);   // 4 MB
  float* proj   = (float*)(ws + 0*MB);  // 8 MB   [qkv dead by then; dead after ln1]
  float* x      = (float*)(ws + 8*MB);  // 8 MB   [persists]
  u16*   x_hi   = (u16*)(ws + 16*MB);   // 4 MB   [dead after FFN1]
  u16*   WtA    = (u16*)(ws + 24*MB);   // 32 MB  [MoE weights; Wt3/Vt/ao dead]
  u16*   h      = (u16*)(ws + 56*MB);   // 16 MB  [ao_lo/gb dead]
  float* p0     = (float*)(ws + 0*MB);  // 8 MB   [FFN2 partial; proj dead]
  float* p1     = (float*)(ws + 72*MB); // 8 MB
  int*   e_sel  = (int*)(ws + 80*MB);
  int*   perm   = e_sel + TOK;
  int*   offs   = perm + TOK;
  int*   cnts   = offs + NEXP;

  dim3 blk(256);
  split_kernel<<<2048, blk, 0, stream>>>(src, src_hi, src_lo);

  // fused QKV: Wt3[3072][1024] <- qw|kw|vw (single conversion launch), then
  // one 2048x3072x1024 split GEMM; V columns written directly transposed.
  wt3_conv_kernel<<<dim3(32,1,96), blk, 0, stream>>>(qw, kw, vw, Wt3_hi, Wt3_lo);
  gemm_split_kernel<2,64><<<dim3(48,16), blk, 0, stream>>>(src_hi, src_lo, Wt3_hi, Wt3_lo,
      nullptr, nullptr, nullptr, qkv_hi, qkv_lo, Vt_hi, Vt_lo, TOK, 3072, DMODEL);

  // MFMA flash attention (split-bf16, dynamic scale gate), 8-wave blocks
  attn_mfma_kernel<<<dim3(8, NHEAD, 2), dim3(512), 0, stream>>>(
      qkv_hi, qkv_lo, Vt_hi, Vt_lo, scale_w, ao, ao_hi, ao_lo);

  // gate = sigmoid(ao @ gate_w + gate_b); gbuf = ao * gate (split output)
  wt_conv_kernel<true><<<dim3(32,32,1), blk, 0, stream>>>(gate_w, Wt3_hi, Wt3_lo, DMODEL, DMODEL);
  gemm_split_kernel<1,64><<<dim3(16,16), blk, 0, stream>>>(ao_hi, ao_lo, Wt3_hi, Wt3_lo,
      gate_b, ao, nullptr, gb_hi, gb_lo, nullptr, nullptr, TOK, DMODEL, DMODEL);
  // proj = gbuf @ ow
  wt_conv_kernel<true><<<dim3(32,32,1), blk, 0, stream>>>(ow, Wt3_hi, Wt3_lo, DMODEL, DMODEL);
  gemm_split_kernel<0,64><<<dim3(16,16), blk, 0, stream>>>(gb_hi, gb_lo, Wt3_hi, Wt3_lo,
      nullptr, nullptr, proj, nullptr, nullptr, nullptr, nullptr, TOK, DMODEL, DMODEL);

  // x = LN(src + proj); bf16 copy for MoE A-side
  ln_add_kernel<true><<<TOK, blk, 0, stream>>>(src, proj, n1_g, n1_b, x, x_hi);

  // router (fp32) + grouping
  moe_gate_kernel<<<TOK/4, blk, 0, stream>>>(x, mgw, mgb, e_sel);
  moe_group_kernel<<<1, blk, 0, stream>>>(e_sel, perm, offs, cnts);

  // FFN1 in two expert-chunks (WtA = 32 MB holds 4 experts)
  for (int c = 0; c < 2; ++c) {
    wt_conv_kernel<false><<<dim3(DFFN/32, DMODEL/32, 4), blk, 0, stream>>>(
        w1 + (size_t)c*4*DMODEL*DFFN, WtA, nullptr, DMODEL, DFFN);
    gemm_moe_kernel<0,128><<<dim3(DFFN/128, 16, 4), blk, 0, stream>>>(
        x_hi, WtA, b1, perm, offs, cnts, h, nullptr, nullptr, DFFN, DMODEL, c*4);
  }
  moe_ln_gelu_kernel<<<TOK, blk, 0, stream>>>(h, ln_g, ln_b, e_sel);
  // FFN2 in two expert-chunks, 2-way split-K (z = ez + 4*ks) -> p0/p1
  for (int c = 0; c < 2; ++c) {
    wt_conv_kernel<false><<<dim3(DMODEL/32, DFFN/32, 4), blk, 0, stream>>>(
        w2 + (size_t)c*4*DFFN*DMODEL, WtA, nullptr, DFFN, DMODEL);
    gemm_moe_kernel<1,64><<<dim3(DMODEL/64, 16, 8), blk, 0, stream>>>(
        h, WtA, nullptr, perm, offs, cnts, nullptr, p0, p1, DMODEL, DFFN, c*4);
  }
  // out = LN(x + ((p0+p1+b2[e])*rs[e] + x), n2)
  ln_final_kernel<<<TOK, blk, 0, stream>>>(x, p0, p1, b2, rs, e_sel, n2_g, n2_b, (float*)d_out);
}